// Round 11
// baseline (38784.933 us; speedup 1.0000x reference)
//
#include <hip/hip_runtime.h>
#include <stdint.h>

typedef unsigned int u32;
typedef unsigned long long u64;
typedef unsigned short u16;

typedef __attribute__((ext_vector_type(8))) short short8;
typedef __attribute__((ext_vector_type(4))) float f32x4;

#define AT_LD32(p)    __hip_atomic_load((u32*)(p), __ATOMIC_RELAXED, __HIP_MEMORY_SCOPE_AGENT)
#define AT_ST32(p,v)  __hip_atomic_store((u32*)(p), (v), __ATOMIC_RELAXED, __HIP_MEMORY_SCOPE_AGENT)
#define AT_LD64(p)    __hip_atomic_load((u64*)(p), __ATOMIC_RELAXED, __HIP_MEMORY_SCOPE_AGENT)
#define AT_ST64(p,v)  __hip_atomic_store((u64*)(p), (v), __ATOMIC_RELAXED, __HIP_MEMORY_SCOPE_AGENT)
#define AT_ADD32(p,v) __hip_atomic_fetch_add((u32*)(p), (v), __ATOMIC_RELAXED, __HIP_MEMORY_SCOPE_AGENT)

__device__ __forceinline__ float sigf(float x){ return 1.0f/(1.0f+__expf(-x)); }
__device__ __forceinline__ float tanhfast(float x){ float e=__expf(2.0f*x); return (e-1.0f)/(e+1.0f); }

__device__ __forceinline__ u32 pk2(float a, float b){
  u32 ua=__float_as_uint(a), ub=__float_as_uint(b);
  ua = (ua + 0x7fffu + ((ua>>16)&1u)) >> 16;
  ub = (ub + 0x7fffu + ((ub>>16)&1u)) >> 16;
  return ua | (ub<<16);
}
__device__ __forceinline__ u32 bf16bits(float a){
  u32 ua=__float_as_uint(a);
  return (ua + 0x7fffu + ((ua>>16)&1u)) >> 16;
}
__device__ __forceinline__ float lo16(u32 u){ return __uint_as_float(u<<16); }
__device__ __forceinline__ float hi16(u32 u){ return __uint_as_float(u & 0xffff0000u); }

__device__ __forceinline__ f32x4 mfma16(short8 a, short8 b, f32x4 c){
  return __builtin_amdgcn_mfma_f32_16x16x32_bf16(a, b, c, 0, 0, 0);
}
union U4S8 { uint4 u; short8 s; };

// dependent-VALU delay (~10 cyc/iter). Keeps the CU busy (DVFS) and paces
// LLC poll rounds without s_sleep wake latency. Loop structure of the
// surrounding spins is unchanged from the passing rounds.
__device__ __forceinline__ void vdelay(int n){
  float x = 1.0f + (float)(threadIdx.x & 7);
  #pragma unroll 1
  for (int k = 0; k < n; ++k)
    asm volatile("v_sqrt_f32 %0, %0" : "+v"(x));
  asm volatile("" :: "v"(x));
}

// ---- LLC-tier loads (sc0 sc1 = bypass L1+L2, read at device coherence point).
// Load + waitcnt stay INSIDE one asm block (separating them lets hipcc hoist
// register reads past the waitcnt — the round-10 failure).
__device__ __forceinline__ uint4 ld128_llc(const u32* p){
  uint4 r;
  asm volatile("global_load_dwordx4 %0, %1, off sc0 sc1\n\ts_waitcnt vmcnt(0)"
               : "=v"(r) : "v"(p) : "memory");
  return r;
}
__device__ __forceinline__ void ld8_llc(const u32* p,
    uint4& r0, uint4& r1, uint4& r2, uint4& r3,
    uint4& r4, uint4& r5, uint4& r6, uint4& r7)
{
  const u32 *p0=p, *p1=p+2048, *p2=p+4096, *p3=p+6144,
            *p4=p+8192, *p5=p+10240, *p6=p+12288, *p7=p+14336;
  asm volatile(
    "global_load_dwordx4 %0, %8, off sc0 sc1\n\t"
    "global_load_dwordx4 %1, %9, off sc0 sc1\n\t"
    "global_load_dwordx4 %2, %10, off sc0 sc1\n\t"
    "global_load_dwordx4 %3, %11, off sc0 sc1\n\t"
    "global_load_dwordx4 %4, %12, off sc0 sc1\n\t"
    "global_load_dwordx4 %5, %13, off sc0 sc1\n\t"
    "global_load_dwordx4 %6, %14, off sc0 sc1\n\t"
    "global_load_dwordx4 %7, %15, off sc0 sc1\n\t"
    "s_waitcnt vmcnt(0)"
    : "=&v"(r0), "=&v"(r1), "=&v"(r2), "=&v"(r3),
      "=&v"(r4), "=&v"(r5), "=&v"(r6), "=&v"(r7)
    : "v"(p0), "v"(p1), "v"(p2), "v"(p3), "v"(p4), "v"(p5), "v"(p6), "v"(p7)
    : "memory");
}

// ---- 2-level grid barrier (encoder only)
__device__ __forceinline__ void gbar(u32* ctrl, volatile int* bail){
  asm volatile("s_waitcnt vmcnt(0) lgkmcnt(0)" ::: "memory");
  __syncthreads();
  if (threadIdx.x == 0){
    u32* GEN = ctrl + 9*32;
    u32 g = AT_LD32(GEN);
    int leaf = blockIdx.x & 7;
    u32 n = AT_ADD32(ctrl + leaf*32, 1u);
    if (n == 31u){
      AT_ST32(ctrl + leaf*32, 0u);
      u32 r = AT_ADD32(ctrl + 8*32, 1u);
      if (r == 7u){ AT_ST32(ctrl + 8*32, 0u); AT_ADD32(GEN, 1u); }
    }
    long lim = (*bail) ? (1L<<8) : (1L<<22);
    long c = 0;
    while (AT_LD32(GEN) == g){
      __builtin_amdgcn_s_sleep(2);
      if (++c > lim){ *bail = 1; break; }
    }
  }
  __syncthreads();
}

__global__ void init_ctrl(u32* ws0){
  // donew (64 rows x 256 u32 = 64KB) at ws+4096; ctrl (320 u32) at ws+0
  int idx = blockIdx.x*512 + threadIdx.x;          // grid 32 x 512 = 16384
  ws0[1024 + idx] = 0u;
  if (blockIdx.x == 0 && threadIdx.x < 320) ws0[threadIdx.x] = 0u;
}

__global__ void embed_k(const int* __restrict__ x, const float* __restrict__ emb,
                        float* __restrict__ emb_x){
  int gid = blockIdx.x*256 + threadIdx.x;   // 64*32*512
  int k  = gid & 511;
  int tb = gid >> 9;
  emb_x[gid] = emb[(size_t)x[tb]*512 + k];
}

// f32 -> bf16 row convert (first 512 of srcStride cols)
__global__ void conv_bf16_k(const float* __restrict__ src, int srcStride, u16* __restrict__ dst){
  int idx = blockIdx.x*256 + threadIdx.x;   // 2560*256
  int r = idx >> 8, kp = idx & 255;
  const float* s = src + (size_t)r*srcStride + kp*2;
  ((u32*)dst)[r*256 + kp] = pk2(s[0], s[1]);
}

// C[m][n] = bias + sum_k A[m*lda+k]*B[n*ldb+boff+k]; grid=(N/256, M/8)
__global__ __launch_bounds__(256) void gemm_f32(
    const float* __restrict__ A, int lda,
    const float* __restrict__ Bm, int ldb, int boff,
    const float* __restrict__ bias, int biasOnM,
    float* __restrict__ C, int ldc, int K)
{
  __shared__ float As[8][1028];
  int n  = blockIdx.x*256 + threadIdx.x;
  int m0 = blockIdx.y*8;
  for (int idx = threadIdx.x; idx < 8*K; idx += 256){
    int mm = idx / K, kk = idx - mm*K;
    As[mm][kk] = A[(size_t)(m0+mm)*lda + kk];
  }
  __syncthreads();
  float acc[8];
  if (biasOnM){
    #pragma unroll
    for (int mm=0; mm<8; ++mm) acc[mm] = bias[m0+mm];
  } else {
    float bs = bias[n];
    #pragma unroll
    for (int mm=0; mm<8; ++mm) acc[mm] = bs;
  }
  const float* bp = Bm + (size_t)n*ldb + boff;
  for (int k = 0; k < K; k += 4){
    float4 w = *(const float4*)(bp + k);
    #pragma unroll
    for (int mm = 0; mm < 8; ++mm)
      acc[mm] += As[mm][k]*w.x + As[mm][k+1]*w.y + As[mm][k+2]*w.z + As[mm][k+3]*w.w;
  }
  #pragma unroll
  for (int mm = 0; mm < 8; ++mm)
    C[(size_t)(m0+mm)*ldc + n] = acc[mm];
}

// ---------------- persistent bidirectional encoder (unchanged) ----------------
__global__ __launch_bounds__(512) void enc_persist(
    const float* __restrict__ Whh_f, const float* __restrict__ Whh_b,
    const float* __restrict__ Gx_f,  const float* __restrict__ Gx_b,
    float* __restrict__ h_cat, u32* ctrl, u32* hbuf)
{
  __shared__ __align__(16) u32 uni[32*268];
  __shared__ __align__(16) u32 wldsb[16*256];
  __shared__ float clds[128];
  __shared__ float exch[128];
  __shared__ int bail;

  const int tid = threadIdx.x, bid = blockIdx.x;
  const int dir = bid >> 7, dblk = bid & 127, d0 = dblk*4;
  const int b = tid & 31, grp = tid >> 5;
  const int dL = grp & 3, ks = grp >> 2;
  if (tid == 0) bail = 0;

  const float* Whh = dir ? Whh_b : Whh_f;
  const float* Gx  = dir ? Gx_b  : Gx_f;

  for (int idx = tid; idx < 16*256; idx += 512){
    int r = idx >> 8, p = idx & 255;
    int g = r >> 2, dl = r & 3;
    const float* wr = Whh + (size_t)(g*512 + d0 + dl)*512 + p*2;
    wldsb[idx] = pk2(wr[0], wr[1]);
  }

  u32* hb = hbuf + dir*2*8192;

  for (int t = 0; t < 64; ++t){
    int teff = dir ? (63 - t) : t;
    if (t > 0){
      const u32* src = hb + ((t&1)<<13);
      for (int idx = tid; idx < 8192; idx += 512)
        uni[(idx&31)*268 + (idx>>5)] = AT_LD32(src + idx);
    }
    __syncthreads();
    float a0=0.f,a1=0.f,a2=0.f,a3=0.f;
    if (t > 0){
      const u32* srow = uni + b*268 + ks*64;
      for (int c4 = 0; c4 < 16; ++c4){
        uint4 s4 = *(const uint4*)(srow + c4*4);
        float f0=lo16(s4.x),f1=hi16(s4.x),f2=lo16(s4.y),f3=hi16(s4.y);
        float f4=lo16(s4.z),f5=hi16(s4.z),f6=lo16(s4.w),f7=hi16(s4.w);
        int kp = ks*64 + c4*4;
        #pragma unroll
        for (int g = 0; g < 4; ++g){
          uint4 wq = *(const uint4*)(wldsb + (g*4+dL)*256 + kp);
          float s = f0*lo16(wq.x)+f1*hi16(wq.x)+f2*lo16(wq.y)+f3*hi16(wq.y)
                  + f4*lo16(wq.z)+f5*hi16(wq.z)+f6*lo16(wq.w)+f7*hi16(wq.w);
          if (g==0) a0+=s; else if (g==1) a1+=s; else if (g==2) a2+=s; else a3+=s;
        }
      }
    }
    __syncthreads();
    float* part = (float*)uni;
    { int base=(grp*32+b)*4; part[base]=a0; part[base+1]=a1; part[base+2]=a2; part[base+3]=a3; }
    __syncthreads();
    if (tid < 128){
      int bb = tid & 31, dl = tid >> 5;
      float r0=0.f,r1=0.f,r2=0.f,r3=0.f;
      #pragma unroll
      for (int kk = 0; kk < 4; ++kk){
        const float* p4 = part + (((kk<<2)|dl)*32 + bb)*4;
        r0+=p4[0]; r1+=p4[1]; r2+=p4[2]; r3+=p4[3];
      }
      const float* gx = Gx + ((size_t)teff*32 + bb)*2048;
      int d = d0 + dl;
      float gi=r0+gx[d], gf=r1+gx[512+d], gg=r2+gx[1024+d], go=r3+gx[1536+d];
      float c_ = (t==0) ? 0.f : clds[tid];
      float cn = sigf(gf)*c_ + sigf(gi)*tanhfast(gg);
      float hn = sigf(go)*tanhfast(cn);
      clds[tid] = cn;
      exch[tid] = hn;
      h_cat[((size_t)teff*32 + bb)*1024 + dir*512 + d] = hn;
    }
    __syncthreads();
    if (tid < 64){
      int bb = tid & 31, pp = tid >> 5;
      u32 u = pk2(exch[(pp*2)*32 + bb], exch[(pp*2+1)*32 + bb]);
      AT_ST32(hb + (((t+1)&1)<<13) + (dblk*2 + pp)*32 + bb, u);
    }
    gbar(ctrl, &bail);
  }
}

// ---------------- decoder v11: r8 spin + bounded retries + VALU pacing ----------------
// sstream: 64 slots x 16384 u32; word (bb,d) of slot j = (tag<<16)|bf16(s), tag = i*64+j+1.
// Producers: 1 dword atomic store per gate thread (fire-and-forget; r8-proven).
// Consumers: round 0 = ld8_llc (8 loads + waitcnt in ONE asm block, r8-proven);
// retry rounds = per-pending ld128_llc (waitcnt inside, r7-proven) + vdelay pacing
// -> poll traffic bounded (kills the r8 6.8TB/s refetch storm / 532ms outlier).
extern __shared__ __align__(16) char dynlds[];

// LAYOUT 0: logits [32][257]-u32 u16 layout; LAYOUT 1: cells swizzled A-layout.
template<int LAYOUT>
__device__ __forceinline__ void xspin_llc(const u32* __restrict__ slot, u32 etag,
                                          u16* __restrict__ lds16, int tid,
                                          volatile int* bail)
{
  const u32* p = slot + tid*4;
  uint4 q0,q1,q2,q3,q4,q5,q6,q7;
  u32* lds32 = (u32*)lds16;
  u64* lds64 = (u64*)lds16;
  auto proc = [&](int K, const uint4& V)->bool{
    bool ok = ((V.x>>16)==etag) & ((V.y>>16)==etag) & ((V.z>>16)==etag) & ((V.w>>16)==etag);
    if (ok){
      int idx = tid*4 + K*2048;          // u32 word index == u16 payload index
      int ab = idx >> 9, ad = idx & 511; // ab = batch row, ad = d (multiple of 4)
      if (LAYOUT){
        u64 pk = (u64)(V.x & 0xffffu) | ((u64)(V.y & 0xffffu) << 16)
               | ((u64)(V.z & 0xffffu) << 32) | ((u64)(V.w & 0xffffu) << 48);
        lds64[(ab*512 + (ad ^ ((ab&7)<<3))) >> 2] = pk;
      } else {
        int base = ab*514 + ad;          // even
        lds32[base >> 1]       = (V.x & 0xffffu) | ((V.y & 0xffffu) << 16);
        lds32[(base >> 1) + 1] = (V.z & 0xffffu) | ((V.w & 0xffffu) << 16);
      }
    }
    return ok;
  };
  // round 0: bulk fetch, all 8 granules in flight, one waitcnt
  u32 pend = 0xFFu;
  ld8_llc(p, q0,q1,q2,q3,q4,q5,q6,q7);
  if (proc(0,q0)) pend &= ~1u;
  if (proc(1,q1)) pend &= ~2u;
  if (proc(2,q2)) pend &= ~4u;
  if (proc(3,q3)) pend &= ~8u;
  if (proc(4,q4)) pend &= ~16u;
  if (proc(5,q5)) pend &= ~32u;
  if (proc(6,q6)) pend &= ~64u;
  if (proc(7,q7)) pend &= ~128u;
  // retry rounds: only pending granules, paced
  long lim = (*bail) ? (1L<<8) : (1L<<19);
  long cc = 0;
  while (pend){
    vdelay(12);
    #pragma unroll
    for (int k = 0; k < 8; ++k){
      if (pend & (1u<<k)){
        uint4 v = ld128_llc(p + k*2048);
        if (proc(k, v)) pend &= ~(1u<<k);
      }
    }
    if (++cc > lim){ *bail = 1; break; }
  }
}

// B from global (y-part, Wxbf)
__device__ __forceinline__ void mfma_phase_g(const u32* __restrict__ sldsp,
    const u16* __restrict__ Bw, float* __restrict__ dst,
    int lane, int mtile, int nt0, int nB, int d0)
{
  const int mrow  = mtile*16 + (lane & 15);
  const int abase = mrow*256;
  const int asw   = (mrow & 7) << 2;
  const int ddc   = lane & 15;
  const size_t br0 = ((size_t)(nt0*512 + d0 + ddc)) * 512;
  const size_t br1 = ((size_t)((nt0+1)*512 + d0 + ddc)) * 512;
  const int kl = (lane >> 4) * 8;
  f32x4 acc0 = {0.f,0.f,0.f,0.f}, acc1 = {0.f,0.f,0.f,0.f};
  #pragma unroll
  for (int ks = 0; ks < 16; ++ks){
    const int dw = ks*16 + (lane>>4)*4;
    U4S8 a;  a.u  = *(const uint4*)&sldsp[abase + (dw ^ asw)];
    U4S8 b0; b0.u = *(const uint4*)(Bw + br0 + ks*32 + kl);
    acc0 = mfma16(a.s, b0.s, acc0);
    if (nB > 1){
      U4S8 b1; b1.u = *(const uint4*)(Bw + br1 + ks*32 + kl);
      acc1 = mfma16(a.s, b1.s, acc1);
    }
  }
  { float* p = &dst[(nt0*16 + ddc)*36 + mtile*16 + ((lane>>4)<<2)]; *(f32x4*)p = acc0; }
  if (nB > 1){
    float* p = &dst[((nt0+1)*16 + ddc)*36 + mtile*16 + ((lane>>4)<<2)]; *(f32x4*)p = acc1;
  }
}

// B from LDS (recurrence, wsl)
__device__ __forceinline__ void mfma_phase_lds(const u32* __restrict__ sldsp,
    const u16* __restrict__ wsl, float* __restrict__ dst,
    int lane, int mtile, int nt0, int nB)
{
  const int mrow  = mtile*16 + (lane & 15);
  const int abase = mrow*256;
  const int asw   = (mrow & 7) << 2;
  const int ddc   = lane & 15;
  const int kl = (lane >> 4) * 8;
  const int bsw = (ddc & 7) << 3;
  const u16* B0 = wsl + (nt0*16 + ddc)*512;
  const u16* B1 = wsl + ((nt0+1)*16 + ddc)*512;
  f32x4 acc0 = {0.f,0.f,0.f,0.f}, acc1 = {0.f,0.f,0.f,0.f};
  #pragma unroll
  for (int ks = 0; ks < 16; ++ks){
    const int dw = ks*16 + (lane>>4)*4;
    const int bk = (ks*32 + kl) ^ bsw;
    U4S8 a;  a.u  = *(const uint4*)&sldsp[abase + (dw ^ asw)];
    U4S8 b0; b0.u = *(const uint4*)(B0 + bk);
    acc0 = mfma16(a.s, b0.s, acc0);
    if (nB > 1){
      U4S8 b1; b1.u = *(const uint4*)(B1 + bk);
      acc1 = mfma16(a.s, b1.s, acc1);
    }
  }
  { float* p = &dst[(nt0*16 + ddc)*36 + mtile*16 + ((lane>>4)<<2)]; *(f32x4*)p = acc0; }
  if (nB > 1){
    float* p = &dst[((nt0+1)*16 + ddc)*36 + mtile*16 + ((lane>>4)<<2)]; *(f32x4*)p = acc1;
  }
}

__global__ __launch_bounds__(512) void dec_persist(
    const u16* __restrict__ Wsbf, const u16* __restrict__ Wxbf,
    const float* __restrict__ Wl, const float* __restrict__ bl,
    const float* __restrict__ emb, const float* __restrict__ hpartT,
    u32* donew, u64* bests, u32* sstream, float* __restrict__ out)
{
  __shared__ int bail;
  const int tid = threadIdx.x, bid = blockIdx.x;
  if (tid == 0) bail = 0;
  __syncthreads();

  if (bid < 32){
    // ================= cell blocks: 16 s-dims each, LDS-resident Ws =================
    u16*   wsl  = (u16*)dynlds;
    u32*   slds = (u32*)(dynlds + 81920);
    float* pre  = (float*)(dynlds + 114688);
    float* ypl  = (float*)(dynlds + 126208);
    u64*   kred = (u64*)(dynlds + 137728);
    int*   tokl = (int*)(dynlds + 141824);

    const int w = tid >> 6, l = tid & 63;
    const int mtile = w & 1, ng = w >> 1;
    const int nt0 = (ng == 0) ? 0 : (ng + 1);
    const int nB  = (ng == 0) ? 2 : 1;
    const int bb = tid >> 4, dd = tid & 15;
    const int d0 = bid * 16;
    u16* lds16 = (u16*)slds;
    float creg = 0.f;

    // load & swizzle this block's Ws slice into LDS (once)
    for (int idx = tid; idx < 80*512; idx += 512){
      int c = idx >> 9, k = idx & 511;
      int col = (c >> 4)*512 + d0 + (c & 15);
      wsl[c*512 + (k ^ ((c&7)<<3))] = Wsbf[(size_t)col*512 + k];
    }
    __syncthreads();

    for (int i = 0; i < 64; ++i){
      if (i == 0){
        for (int idx = tid; idx < 2880; idx += 512) ypl[idx] = 0.f;
        __syncthreads();
      } else {
        // wait for logits row i-1 (224 tagged flag words, no RMW)
        if (tid < 224){
          const u32 M = 0x44450000u | (u32)(i-1);
          long cc = 0;
          while (AT_LD32(donew + (size_t)(i-1)*256 + tid) != M){
            vdelay(24);
            if (++cc > (1L<<22)){ bail = 1; break; }
          }
        }
        __syncthreads();
        // reduce per-logits-block argmax keys -> tokens
        {
          int rb = tid >> 4, part = tid & 15;
          u64 m = 0;
          const u64* bp = bests + (size_t)rb*224 + part*14;
          #pragma unroll
          for (int q = 0; q < 14; ++q){ u64 x = AT_LD64(bp + q); if (x > m) m = x; }
          kred[rb*16 + part] = m;
        }
        __syncthreads();
        if (tid < 32){
          u64 m = 0;
          #pragma unroll
          for (int q = 0; q < 16; ++q){ u64 x = kred[tid*16 + q]; if (x > m) m = x; }
          int tk = (int)(~(u32)m);
          tk = tk < 0 ? 0 : (tk > 31999 ? 31999 : tk);
          tokl[tid] = tk;
        }
        __syncthreads();
        // y embedding -> LDS -> y-part MFMA (B = Wxbf from global/L2)
        for (int idx = tid; idx < 8192; idx += 512){
          int eb = idx >> 8, dp = idx & 255;
          const float* er = emb + (size_t)tokl[eb]*512 + dp*2;
          slds[eb*256 + (dp ^ ((eb&7)<<2))] = pk2(er[0], er[1]);
        }
        __syncthreads();
        mfma_phase_g(slds, Wxbf, ypl, l, mtile, nt0, nB, d0);
        __syncthreads();
      }
      creg = 0.f;

      for (int j = 0; j < 64; ++j){
        const u32 gtag = (u32)(i*64 + j + 1);
        float hp[5];
        {
          const float* hb = hpartT + (size_t)(d0 + dd)*2048 + j*32 + bb;
          #pragma unroll
          for (int q = 0; q < 5; ++q) hp[q] = hb[(size_t)q*512*2048];
        }
        if (j > 0){
          xspin_llc<1>(sstream + (size_t)(j-1)*16384, (u32)(i*64 + j), lds16, tid, &bail);
          __syncthreads();
          mfma_phase_lds(slds, wsl, pre, l, mtile, nt0, nB);
        }
        __syncthreads();
        // gates: thread (bb, dd)
        {
          float pv[5];
          #pragma unroll
          for (int q = 0; q < 5; ++q){
            float x = ypl[(q*16 + dd)*36 + bb] + hp[q];
            if (j > 0) x += pre[(q*16 + dd)*36 + bb];
            pv[q] = x;
          }
          float gi = sigf(pv[0]), gf = sigf(pv[1]), go = sigf(pv[2]), gl = sigf(pv[3]);
          float cn = gf * (gl * creg) + gi * tanhfast(pv[4]);
          creg = cn;
          float sn = go * tanhfast(cn);
          AT_ST32(sstream + (size_t)j*16384 + bb*512 + d0 + dd, (gtag<<16) | bf16bits(sn));
        }
        // no fence, no flag, no trailing sync
      }
    }
  } else {
    // ================= logits blocks =================
    u32*   uni  = (u32*)dynlds;
    float* lred = (float*)(dynlds + 32896);
    u64*   kredl= (u64*)(dynlds + 51904);

    const int lb = bid - 32;
    const int v0 = lb * 143;
    int nv = 32000 - v0; if (nv > 143) nv = 143;
    const int grp = tid >> 5, b = tid & 31;
    u16* lu16 = (u16*)uni;
    const u32* slot63 = sstream + (size_t)63*16384;
    const int sidx = (lb*73 + 17) & 16383;

    for (int i = 0; i < 64; ++i){
      const u32 etag = (u32)(i*64 + 64);
      // cheap sentinel poll first (keeps 224 blocks off the slot until ready)
      if (tid == 0){
        long cc = 0;
        while ((AT_LD32(slot63 + sidx) >> 16) != etag){
          vdelay(48);
          if (++cc > (1L<<22)){ bail = 1; break; }
        }
      }
      __syncthreads();
      xspin_llc<0>(slot63, etag, lu16, tid, &bail);
      __syncthreads();
      float acc[9];
      #pragma unroll
      for (int t = 0; t < 9; ++t){
        int vt = grp + 16*t;
        acc[t] = (vt < nv) ? bl[v0 + vt] : -1e30f;
      }
      const u32* srow = uni + b*257;
      for (int pp = 0; pp < 128; ++pp){
        u32 u0 = srow[pp*2], u1 = srow[pp*2 + 1];
        float f0 = lo16(u0), f1 = hi16(u0), f2 = lo16(u1), f3 = hi16(u1);
        #pragma unroll
        for (int t = 0; t < 9; ++t){
          int vt = grp + 16*t;
          if (vt < nv){
            const float4 w4 = *(const float4*)(Wl + (size_t)(v0 + vt)*512 + pp*4);
            acc[t] += f0*w4.x + f1*w4.y + f2*w4.z + f3*w4.w;
          }
        }
      }
      u64 best = 0;
      #pragma unroll
      for (int t = 0; t < 9; ++t){
        int vt = grp + 16*t;
        if (vt < nv){
          lred[vt*33 + b] = acc[t];
          u32 su = __float_as_uint(acc[t]);
          su = (su >> 31) ? ~su : (su | 0x80000000u);
          u64 key = ((u64)su << 32) | (u32)(~(u32)(v0 + vt));
          if (key > best) best = key;
        }
      }
      kredl[grp*32 + b] = best;
      __syncthreads();
      if (tid < 32){
        u64 m = 0;
        #pragma unroll
        for (int q2 = 0; q2 < 16; ++q2){ u64 x = kredl[q2*32 + tid]; if (x > m) m = x; }
        AT_ST64(bests + (size_t)tid*224 + lb, m);
      }
      asm volatile("s_waitcnt vmcnt(0)" ::: "memory");   // bests visible before flag
      if (tid == 0) AT_ST32(donew + (size_t)i*256 + lb, 0x44450000u | (u32)i);
      // output writes AFTER the flag (off the critical path)
      const size_t obase = ((size_t)i*32)*32000 + v0;
      for (int bb2 = 0; bb2 < 32; ++bb2){
        for (int v = tid; v < nv; v += 512)
          out[obase + (size_t)bb2*32000 + v] = lred[v*33 + bb2];
      }
    }
  }
}

__global__ __launch_bounds__(256) void softmax_k(float* __restrict__ out){
  size_t row = blockIdx.x;
  float* p = out + row*32000;
  __shared__ float red[256];
  float s = 0.f;
  for (int v = threadIdx.x; v < 32000; v += 256) s += __expf(p[v]);
  red[threadIdx.x] = s;
  __syncthreads();
  for (int off = 128; off > 0; off >>= 1){
    if (threadIdx.x < off) red[threadIdx.x] += red[threadIdx.x+off];
    __syncthreads();
  }
  float Z = red[0];
  for (int v = threadIdx.x; v < 32000; v += 256) p[v] = __expf(p[v]) / Z;
}

extern "C" void kernel_launch(void* const* d_in, const int* in_sizes, int n_in,
                              void* d_out, int out_size, void* d_ws, size_t ws_size,
                              hipStream_t stream)
{
  const int*   x    = (const int*)d_in[0];
  const float* emb  = (const float*)d_in[2];
  const float* Wihf = (const float*)d_in[3];
  const float* Whhf = (const float*)d_in[4];
  const float* bf   = (const float*)d_in[5];
  const float* Wihb = (const float*)d_in[6];
  const float* Whhb = (const float*)d_in[7];
  const float* bb   = (const float*)d_in[8];
  const float* Wx   = (const float*)d_in[9];
  const float* Ws   = (const float*)d_in[10];
  const float* bc   = (const float*)d_in[11];
  const float* Wl   = (const float*)d_in[12];
  const float* bl   = (const float*)d_in[13];

  char* ws = (char*)d_ws;
  u32* ctrl    = (u32*)ws;                      // 1280 B (encoder gbar)
  u32* donew   = (u32*)(ws + 4096);             // 64 x 256 u32 = 64 KB -> 69632
  u64* bests   = (u64*)(ws + 69632);            // 32 x 224 u64 = 56 KB -> 126976
  u32* sstream = (u32*)(ws + 131072);           // 64 x 16384 u32 = 4 MB -> 4325376
  u32* hbuf    = (u32*)(ws + 4325376);          // 128 KB -> 4456448
  float* emb_x = (float*)(ws + 4456448);        // 4 MB  -> 8650752
  float* h_cat = (float*)(ws + 8650752);        // 8 MB  -> 17039360
  float* GxfP  = (float*)(ws + 17039360);       // 16 MB -> 33816576
  float* GxbP  = (float*)(ws + 33816576);       // 16 MB -> 50593792
  float* hpartT = GxfP;                         // 2560x2048 f32 = 21 MB (Gx dead after encoder)
  u16* Wsbf = (u16*)emb_x;                      // 2.6 MB (emb_x dead after Gx gemms)
  u16* Wxbf = (u16*)h_cat;                      // 2.6 MB (h_cat dead after hpartT gemm)

  hipFuncSetAttribute((const void*)dec_persist,
                      hipFuncAttributeMaxDynamicSharedMemorySize, 141952);

  hipLaunchKernelGGL(init_ctrl, dim3(32), dim3(512), 0, stream, (u32*)ws);
  hipLaunchKernelGGL(embed_k, dim3(4096), dim3(256), 0, stream, x, emb, emb_x);
  hipLaunchKernelGGL(gemm_f32, dim3(8,256), dim3(256), 0, stream,
                     emb_x, 512, Wihf, 512, 0, bf, 0, GxfP, 2048, 512);
  hipLaunchKernelGGL(gemm_f32, dim3(8,256), dim3(256), 0, stream,
                     emb_x, 512, Wihb, 512, 0, bb, 0, GxbP, 2048, 512);
  hipLaunchKernelGGL(enc_persist, dim3(256), dim3(512), 0, stream,
                     Whhf, Whhb, GxfP, GxbP, h_cat, ctrl, hbuf);
  // hpartT[c][t*32+b] = bc[c] + sum_k Wx[c*1536+512+k] * h_cat[(t*32+b)*1024+k]
  hipLaunchKernelGGL(gemm_f32, dim3(8,320), dim3(256), 0, stream,
                     Wx + 512, 1536, h_cat, 1024, 0, bc, 1, hpartT, 2048, 1024);
  hipLaunchKernelGGL(conv_bf16_k, dim3(2560), dim3(256), 0, stream, Ws, 1024, Wsbf);
  hipLaunchKernelGGL(conv_bf16_k, dim3(2560), dim3(256), 0, stream, Wx, 1536, Wxbf);
  hipLaunchKernelGGL(dec_persist, dim3(256), dim3(512), 141952, stream,
                     Wsbf, Wxbf, Wl, bl, emb, hpartT, donew, bests, sstream, (float*)d_out);
  hipLaunchKernelGGL(softmax_k, dim3(2048), dim3(256), 0, stream, (float*)d_out);
}

// Round 12
// 33561.984 us; speedup vs baseline: 1.1556x; 1.1556x over previous
//
#include <hip/hip_runtime.h>
#include <stdint.h>

typedef unsigned int u32;
typedef unsigned long long u64;
typedef unsigned short u16;

typedef __attribute__((ext_vector_type(8))) short short8;
typedef __attribute__((ext_vector_type(4))) float f32x4;

#define AT_LD32(p)    __hip_atomic_load((u32*)(p), __ATOMIC_RELAXED, __HIP_MEMORY_SCOPE_AGENT)
#define AT_ST32(p,v)  __hip_atomic_store((u32*)(p), (v), __ATOMIC_RELAXED, __HIP_MEMORY_SCOPE_AGENT)
#define AT_LD64(p)    __hip_atomic_load((u64*)(p), __ATOMIC_RELAXED, __HIP_MEMORY_SCOPE_AGENT)
#define AT_ST64(p,v)  __hip_atomic_store((u64*)(p), (v), __ATOMIC_RELAXED, __HIP_MEMORY_SCOPE_AGENT)
#define AT_ADD32(p,v) __hip_atomic_fetch_add((u32*)(p), (v), __ATOMIC_RELAXED, __HIP_MEMORY_SCOPE_AGENT)

__device__ __forceinline__ float sigf(float x){ return 1.0f/(1.0f+__expf(-x)); }
__device__ __forceinline__ float tanhfast(float x){ float e=__expf(2.0f*x); return (e-1.0f)/(e+1.0f); }

__device__ __forceinline__ u32 pk2(float a, float b){
  u32 ua=__float_as_uint(a), ub=__float_as_uint(b);
  ua = (ua + 0x7fffu + ((ua>>16)&1u)) >> 16;
  ub = (ub + 0x7fffu + ((ub>>16)&1u)) >> 16;
  return ua | (ub<<16);
}
__device__ __forceinline__ u32 bf16bits(float a){
  u32 ua=__float_as_uint(a);
  return (ua + 0x7fffu + ((ua>>16)&1u)) >> 16;
}
__device__ __forceinline__ float lo16(u32 u){ return __uint_as_float(u<<16); }
__device__ __forceinline__ float hi16(u32 u){ return __uint_as_float(u & 0xffff0000u); }

__device__ __forceinline__ f32x4 mfma16(short8 a, short8 b, f32x4 c){
  return __builtin_amdgcn_mfma_f32_16x16x32_bf16(a, b, c, 0, 0, 0);
}
union U4S8 { uint4 u; short8 s; };

// dependent-VALU delay (~10 cyc/iter). Used ONLY in pathological spin regimes
// (cc > 8 rounds) to break refetch-storm feedback; common-case path is r8-identical.
__device__ __forceinline__ void vdelay(int n){
  float x = 1.0f + (float)(threadIdx.x & 7);
  #pragma unroll 1
  for (int k = 0; k < n; ++k)
    asm volatile("v_sqrt_f32 %0, %0" : "+v"(x));
  asm volatile("" :: "v"(x));
}

// ---- LLC-tier coalesced loads: sc0 sc1 = bypass L1 and L2, read at the
// device coherence point. 8 loads in flight, ONE waitcnt (parallel RTT).
// Load + waitcnt stay INSIDE one asm block (separating them lets hipcc hoist
// register reads past the waitcnt — the round-10 failure).
__device__ __forceinline__ void ld8_llc(const u32* p,
    uint4& r0, uint4& r1, uint4& r2, uint4& r3,
    uint4& r4, uint4& r5, uint4& r6, uint4& r7)
{
  const u32 *p0=p, *p1=p+2048, *p2=p+4096, *p3=p+6144,
            *p4=p+8192, *p5=p+10240, *p6=p+12288, *p7=p+14336;
  asm volatile(
    "global_load_dwordx4 %0, %8, off sc0 sc1\n\t"
    "global_load_dwordx4 %1, %9, off sc0 sc1\n\t"
    "global_load_dwordx4 %2, %10, off sc0 sc1\n\t"
    "global_load_dwordx4 %3, %11, off sc0 sc1\n\t"
    "global_load_dwordx4 %4, %12, off sc0 sc1\n\t"
    "global_load_dwordx4 %5, %13, off sc0 sc1\n\t"
    "global_load_dwordx4 %6, %14, off sc0 sc1\n\t"
    "global_load_dwordx4 %7, %15, off sc0 sc1\n\t"
    "s_waitcnt vmcnt(0)"
    : "=&v"(r0), "=&v"(r1), "=&v"(r2), "=&v"(r3),
      "=&v"(r4), "=&v"(r5), "=&v"(r6), "=&v"(r7)
    : "v"(p0), "v"(p1), "v"(p2), "v"(p3), "v"(p4), "v"(p5), "v"(p6), "v"(p7)
    : "memory");
}

// ---- 2-level grid barrier (encoder only)
__device__ __forceinline__ void gbar(u32* ctrl, volatile int* bail){
  asm volatile("s_waitcnt vmcnt(0) lgkmcnt(0)" ::: "memory");
  __syncthreads();
  if (threadIdx.x == 0){
    u32* GEN = ctrl + 9*32;
    u32 g = AT_LD32(GEN);
    int leaf = blockIdx.x & 7;
    u32 n = AT_ADD32(ctrl + leaf*32, 1u);
    if (n == 31u){
      AT_ST32(ctrl + leaf*32, 0u);
      u32 r = AT_ADD32(ctrl + 8*32, 1u);
      if (r == 7u){ AT_ST32(ctrl + 8*32, 0u); AT_ADD32(GEN, 1u); }
    }
    long lim = (*bail) ? (1L<<8) : (1L<<22);
    long c = 0;
    while (AT_LD32(GEN) == g){
      __builtin_amdgcn_s_sleep(2);
      if (++c > lim){ *bail = 1; break; }
    }
  }
  __syncthreads();
}

__global__ void init_ctrl(u32* ws0){
  // donew (64 rows x 256 u32 = 64KB) at ws+4096; ctrl (320 u32) at ws+0
  int idx = blockIdx.x*512 + threadIdx.x;          // grid 32 x 512 = 16384
  ws0[1024 + idx] = 0u;
  if (blockIdx.x == 0 && threadIdx.x < 320) ws0[threadIdx.x] = 0u;
}

__global__ void embed_k(const int* __restrict__ x, const float* __restrict__ emb,
                        float* __restrict__ emb_x){
  int gid = blockIdx.x*256 + threadIdx.x;   // 64*32*512
  int k  = gid & 511;
  int tb = gid >> 9;
  emb_x[gid] = emb[(size_t)x[tb]*512 + k];
}

// f32 -> bf16 row convert (first 512 of srcStride cols)
__global__ void conv_bf16_k(const float* __restrict__ src, int srcStride, u16* __restrict__ dst){
  int idx = blockIdx.x*256 + threadIdx.x;   // 2560*256
  int r = idx >> 8, kp = idx & 255;
  const float* s = src + (size_t)r*srcStride + kp*2;
  ((u32*)dst)[r*256 + kp] = pk2(s[0], s[1]);
}

// C[m][n] = bias + sum_k A[m*lda+k]*B[n*ldb+boff+k]; grid=(N/256, M/8)
__global__ __launch_bounds__(256) void gemm_f32(
    const float* __restrict__ A, int lda,
    const float* __restrict__ Bm, int ldb, int boff,
    const float* __restrict__ bias, int biasOnM,
    float* __restrict__ C, int ldc, int K)
{
  __shared__ float As[8][1028];
  int n  = blockIdx.x*256 + threadIdx.x;
  int m0 = blockIdx.y*8;
  for (int idx = threadIdx.x; idx < 8*K; idx += 256){
    int mm = idx / K, kk = idx - mm*K;
    As[mm][kk] = A[(size_t)(m0+mm)*lda + kk];
  }
  __syncthreads();
  float acc[8];
  if (biasOnM){
    #pragma unroll
    for (int mm=0; mm<8; ++mm) acc[mm] = bias[m0+mm];
  } else {
    float bs = bias[n];
    #pragma unroll
    for (int mm=0; mm<8; ++mm) acc[mm] = bs;
  }
  const float* bp = Bm + (size_t)n*ldb + boff;
  for (int k = 0; k < K; k += 4){
    float4 w = *(const float4*)(bp + k);
    #pragma unroll
    for (int mm = 0; mm < 8; ++mm)
      acc[mm] += As[mm][k]*w.x + As[mm][k+1]*w.y + As[mm][k+2]*w.z + As[mm][k+3]*w.w;
  }
  #pragma unroll
  for (int mm = 0; mm < 8; ++mm)
    C[(size_t)(m0+mm)*ldc + n] = acc[mm];
}

// ---------------- persistent bidirectional encoder (unchanged) ----------------
__global__ __launch_bounds__(512) void enc_persist(
    const float* __restrict__ Whh_f, const float* __restrict__ Whh_b,
    const float* __restrict__ Gx_f,  const float* __restrict__ Gx_b,
    float* __restrict__ h_cat, u32* ctrl, u32* hbuf)
{
  __shared__ __align__(16) u32 uni[32*268];
  __shared__ __align__(16) u32 wldsb[16*256];
  __shared__ float clds[128];
  __shared__ float exch[128];
  __shared__ int bail;

  const int tid = threadIdx.x, bid = blockIdx.x;
  const int dir = bid >> 7, dblk = bid & 127, d0 = dblk*4;
  const int b = tid & 31, grp = tid >> 5;
  const int dL = grp & 3, ks = grp >> 2;
  if (tid == 0) bail = 0;

  const float* Whh = dir ? Whh_b : Whh_f;
  const float* Gx  = dir ? Gx_b  : Gx_f;

  for (int idx = tid; idx < 16*256; idx += 512){
    int r = idx >> 8, p = idx & 255;
    int g = r >> 2, dl = r & 3;
    const float* wr = Whh + (size_t)(g*512 + d0 + dl)*512 + p*2;
    wldsb[idx] = pk2(wr[0], wr[1]);
  }

  u32* hb = hbuf + dir*2*8192;

  for (int t = 0; t < 64; ++t){
    int teff = dir ? (63 - t) : t;
    if (t > 0){
      const u32* src = hb + ((t&1)<<13);
      for (int idx = tid; idx < 8192; idx += 512)
        uni[(idx&31)*268 + (idx>>5)] = AT_LD32(src + idx);
    }
    __syncthreads();
    float a0=0.f,a1=0.f,a2=0.f,a3=0.f;
    if (t > 0){
      const u32* srow = uni + b*268 + ks*64;
      for (int c4 = 0; c4 < 16; ++c4){
        uint4 s4 = *(const uint4*)(srow + c4*4);
        float f0=lo16(s4.x),f1=hi16(s4.x),f2=lo16(s4.y),f3=hi16(s4.y);
        float f4=lo16(s4.z),f5=hi16(s4.z),f6=lo16(s4.w),f7=hi16(s4.w);
        int kp = ks*64 + c4*4;
        #pragma unroll
        for (int g = 0; g < 4; ++g){
          uint4 wq = *(const uint4*)(wldsb + (g*4+dL)*256 + kp);
          float s = f0*lo16(wq.x)+f1*hi16(wq.x)+f2*lo16(wq.y)+f3*hi16(wq.y)
                  + f4*lo16(wq.z)+f5*hi16(wq.z)+f6*lo16(wq.w)+f7*hi16(wq.w);
          if (g==0) a0+=s; else if (g==1) a1+=s; else if (g==2) a2+=s; else a3+=s;
        }
      }
    }
    __syncthreads();
    float* part = (float*)uni;
    { int base=(grp*32+b)*4; part[base]=a0; part[base+1]=a1; part[base+2]=a2; part[base+3]=a3; }
    __syncthreads();
    if (tid < 128){
      int bb = tid & 31, dl = tid >> 5;
      float r0=0.f,r1=0.f,r2=0.f,r3=0.f;
      #pragma unroll
      for (int kk = 0; kk < 4; ++kk){
        const float* p4 = part + (((kk<<2)|dl)*32 + bb)*4;
        r0+=p4[0]; r1+=p4[1]; r2+=p4[2]; r3+=p4[3];
      }
      const float* gx = Gx + ((size_t)teff*32 + bb)*2048;
      int d = d0 + dl;
      float gi=r0+gx[d], gf=r1+gx[512+d], gg=r2+gx[1024+d], go=r3+gx[1536+d];
      float c_ = (t==0) ? 0.f : clds[tid];
      float cn = sigf(gf)*c_ + sigf(gi)*tanhfast(gg);
      float hn = sigf(go)*tanhfast(cn);
      clds[tid] = cn;
      exch[tid] = hn;
      h_cat[((size_t)teff*32 + bb)*1024 + dir*512 + d] = hn;
    }
    __syncthreads();
    if (tid < 64){
      int bb = tid & 31, pp = tid >> 5;
      u32 u = pk2(exch[(pp*2)*32 + bb], exch[(pp*2+1)*32 + bb]);
      AT_ST32(hb + (((t+1)&1)<<13) + (dblk*2 + pp)*32 + bb, u);
    }
    gbar(ctrl, &bail);
  }
}

// ---------------- decoder v12: r8 spin (parallel refetch-all) + storm guard ----------------
// sstream: 64 slots x 16384 u32; word (bb,d) of slot j = (tag<<16)|bf16(s), tag = i*64+j+1.
// Producers: 1 dword atomic store per gate thread (fire-and-forget; r8-proven).
// Consumers: EVERY round = 8x dwordx4 in flight + single waitcnt (r8-proven, min
// latency). Pacing (vdelay) engages ONLY after 8 fruitless rounds — bounds the
// refetch-storm feedback (r8's 532ms outlier) without touching the common case.
extern __shared__ __align__(16) char dynlds[];

// LAYOUT 0: logits [32][257]-u32 u16 layout; LAYOUT 1: cells swizzled A-layout.
template<int LAYOUT>
__device__ __forceinline__ void xspin_llc(const u32* __restrict__ slot, u32 etag,
                                          u16* __restrict__ lds16, int tid,
                                          volatile int* bail)
{
  const u32* p = slot + tid*4;
  uint4 q0,q1,q2,q3,q4,q5,q6,q7;
  u32* lds32 = (u32*)lds16;
  u64* lds64 = (u64*)lds16;
  auto proc = [&](int K, const uint4& V)->bool{
    bool ok = ((V.x>>16)==etag) & ((V.y>>16)==etag) & ((V.z>>16)==etag) & ((V.w>>16)==etag);
    if (ok){
      int idx = tid*4 + K*2048;          // u32 word index == u16 payload index
      int ab = idx >> 9, ad = idx & 511; // ab = batch row, ad = d (multiple of 4)
      if (LAYOUT){
        u64 pk = (u64)(V.x & 0xffffu) | ((u64)(V.y & 0xffffu) << 16)
               | ((u64)(V.z & 0xffffu) << 32) | ((u64)(V.w & 0xffffu) << 48);
        lds64[(ab*512 + (ad ^ ((ab&7)<<3))) >> 2] = pk;
      } else {
        int base = ab*514 + ad;          // even
        lds32[base >> 1]       = (V.x & 0xffffu) | ((V.y & 0xffffu) << 16);
        lds32[(base >> 1) + 1] = (V.z & 0xffffu) | ((V.w & 0xffffu) << 16);
      }
    }
    return ok;
  };
  u32 pend = 0xFFu;
  long lim = (*bail) ? (1L<<8) : (1L<<19);
  long cc = 0;
  for(;;){
    ld8_llc(p, q0,q1,q2,q3,q4,q5,q6,q7);   // all 8 in flight, one waitcnt
    if ((pend & 1u)   && proc(0,q0)) pend &= ~1u;
    if ((pend & 2u)   && proc(1,q1)) pend &= ~2u;
    if ((pend & 4u)   && proc(2,q2)) pend &= ~4u;
    if ((pend & 8u)   && proc(3,q3)) pend &= ~8u;
    if ((pend & 16u)  && proc(4,q4)) pend &= ~16u;
    if ((pend & 32u)  && proc(5,q5)) pend &= ~32u;
    if ((pend & 64u)  && proc(6,q6)) pend &= ~64u;
    if ((pend & 128u) && proc(7,q7)) pend &= ~128u;
    if (!pend) break;
    if (++cc > lim){ *bail = 1; break; }
    if (cc > 8) vdelay(16);                // storm guard only; common case untouched
  }
}

// B from global (y-part, Wxbf)
__device__ __forceinline__ void mfma_phase_g(const u32* __restrict__ sldsp,
    const u16* __restrict__ Bw, float* __restrict__ dst,
    int lane, int mtile, int nt0, int nB, int d0)
{
  const int mrow  = mtile*16 + (lane & 15);
  const int abase = mrow*256;
  const int asw   = (mrow & 7) << 2;
  const int ddc   = lane & 15;
  const size_t br0 = ((size_t)(nt0*512 + d0 + ddc)) * 512;
  const size_t br1 = ((size_t)((nt0+1)*512 + d0 + ddc)) * 512;
  const int kl = (lane >> 4) * 8;
  f32x4 acc0 = {0.f,0.f,0.f,0.f}, acc1 = {0.f,0.f,0.f,0.f};
  #pragma unroll
  for (int ks = 0; ks < 16; ++ks){
    const int dw = ks*16 + (lane>>4)*4;
    U4S8 a;  a.u  = *(const uint4*)&sldsp[abase + (dw ^ asw)];
    U4S8 b0; b0.u = *(const uint4*)(Bw + br0 + ks*32 + kl);
    acc0 = mfma16(a.s, b0.s, acc0);
    if (nB > 1){
      U4S8 b1; b1.u = *(const uint4*)(Bw + br1 + ks*32 + kl);
      acc1 = mfma16(a.s, b1.s, acc1);
    }
  }
  { float* p = &dst[(nt0*16 + ddc)*36 + mtile*16 + ((lane>>4)<<2)]; *(f32x4*)p = acc0; }
  if (nB > 1){
    float* p = &dst[((nt0+1)*16 + ddc)*36 + mtile*16 + ((lane>>4)<<2)]; *(f32x4*)p = acc1;
  }
}

// B from LDS (recurrence, wsl)
__device__ __forceinline__ void mfma_phase_lds(const u32* __restrict__ sldsp,
    const u16* __restrict__ wsl, float* __restrict__ dst,
    int lane, int mtile, int nt0, int nB)
{
  const int mrow  = mtile*16 + (lane & 15);
  const int abase = mrow*256;
  const int asw   = (mrow & 7) << 2;
  const int ddc   = lane & 15;
  const int kl = (lane >> 4) * 8;
  const int bsw = (ddc & 7) << 3;
  const u16* B0 = wsl + (nt0*16 + ddc)*512;
  const u16* B1 = wsl + ((nt0+1)*16 + ddc)*512;
  f32x4 acc0 = {0.f,0.f,0.f,0.f}, acc1 = {0.f,0.f,0.f,0.f};
  #pragma unroll
  for (int ks = 0; ks < 16; ++ks){
    const int dw = ks*16 + (lane>>4)*4;
    const int bk = (ks*32 + kl) ^ bsw;
    U4S8 a;  a.u  = *(const uint4*)&sldsp[abase + (dw ^ asw)];
    U4S8 b0; b0.u = *(const uint4*)(B0 + bk);
    acc0 = mfma16(a.s, b0.s, acc0);
    if (nB > 1){
      U4S8 b1; b1.u = *(const uint4*)(B1 + bk);
      acc1 = mfma16(a.s, b1.s, acc1);
    }
  }
  { float* p = &dst[(nt0*16 + ddc)*36 + mtile*16 + ((lane>>4)<<2)]; *(f32x4*)p = acc0; }
  if (nB > 1){
    float* p = &dst[((nt0+1)*16 + ddc)*36 + mtile*16 + ((lane>>4)<<2)]; *(f32x4*)p = acc1;
  }
}

__global__ __launch_bounds__(512) void dec_persist(
    const u16* __restrict__ Wsbf, const u16* __restrict__ Wxbf,
    const float* __restrict__ Wl, const float* __restrict__ bl,
    const float* __restrict__ emb, const float* __restrict__ hpartT,
    u32* donew, u64* bests, u32* sstream, float* __restrict__ out)
{
  __shared__ int bail;
  const int tid = threadIdx.x, bid = blockIdx.x;
  if (tid == 0) bail = 0;
  __syncthreads();

  if (bid < 32){
    // ================= cell blocks: 16 s-dims each, LDS-resident Ws =================
    u16*   wsl  = (u16*)dynlds;
    u32*   slds = (u32*)(dynlds + 81920);
    float* pre  = (float*)(dynlds + 114688);
    float* ypl  = (float*)(dynlds + 126208);
    u64*   kred = (u64*)(dynlds + 137728);
    int*   tokl = (int*)(dynlds + 141824);

    const int w = tid >> 6, l = tid & 63;
    const int mtile = w & 1, ng = w >> 1;
    const int nt0 = (ng == 0) ? 0 : (ng + 1);
    const int nB  = (ng == 0) ? 2 : 1;
    const int bb = tid >> 4, dd = tid & 15;
    const int d0 = bid * 16;
    u16* lds16 = (u16*)slds;
    float creg = 0.f;

    // load & swizzle this block's Ws slice into LDS (once)
    for (int idx = tid; idx < 80*512; idx += 512){
      int c = idx >> 9, k = idx & 511;
      int col = (c >> 4)*512 + d0 + (c & 15);
      wsl[c*512 + (k ^ ((c&7)<<3))] = Wsbf[(size_t)col*512 + k];
    }
    __syncthreads();

    for (int i = 0; i < 64; ++i){
      if (i == 0){
        for (int idx = tid; idx < 2880; idx += 512) ypl[idx] = 0.f;
        __syncthreads();
      } else {
        // wait for logits row i-1 (224 tagged flag words, no RMW)
        if (tid < 224){
          const u32 M = 0x44450000u | (u32)(i-1);
          long cc = 0;
          while (AT_LD32(donew + (size_t)(i-1)*256 + tid) != M){
            __builtin_amdgcn_s_sleep(2);
            if (++cc > (1L<<22)){ bail = 1; break; }
          }
        }
        __syncthreads();
        // reduce per-logits-block argmax keys -> tokens
        {
          int rb = tid >> 4, part = tid & 15;
          u64 m = 0;
          const u64* bp = bests + (size_t)rb*224 + part*14;
          #pragma unroll
          for (int q = 0; q < 14; ++q){ u64 x = AT_LD64(bp + q); if (x > m) m = x; }
          kred[rb*16 + part] = m;
        }
        __syncthreads();
        if (tid < 32){
          u64 m = 0;
          #pragma unroll
          for (int q = 0; q < 16; ++q){ u64 x = kred[tid*16 + q]; if (x > m) m = x; }
          int tk = (int)(~(u32)m);
          tk = tk < 0 ? 0 : (tk > 31999 ? 31999 : tk);
          tokl[tid] = tk;
        }
        __syncthreads();
        // y embedding -> LDS -> y-part MFMA (B = Wxbf from global/L2)
        for (int idx = tid; idx < 8192; idx += 512){
          int eb = idx >> 8, dp = idx & 255;
          const float* er = emb + (size_t)tokl[eb]*512 + dp*2;
          slds[eb*256 + (dp ^ ((eb&7)<<2))] = pk2(er[0], er[1]);
        }
        __syncthreads();
        mfma_phase_g(slds, Wxbf, ypl, l, mtile, nt0, nB, d0);
        __syncthreads();
      }
      creg = 0.f;

      for (int j = 0; j < 64; ++j){
        const u32 gtag = (u32)(i*64 + j + 1);
        float hp[5];
        {
          const float* hb = hpartT + (size_t)(d0 + dd)*2048 + j*32 + bb;
          #pragma unroll
          for (int q = 0; q < 5; ++q) hp[q] = hb[(size_t)q*512*2048];
        }
        if (j > 0){
          xspin_llc<1>(sstream + (size_t)(j-1)*16384, (u32)(i*64 + j), lds16, tid, &bail);
          __syncthreads();
          mfma_phase_lds(slds, wsl, pre, l, mtile, nt0, nB);
        }
        __syncthreads();
        // gates: thread (bb, dd)
        {
          float pv[5];
          #pragma unroll
          for (int q = 0; q < 5; ++q){
            float x = ypl[(q*16 + dd)*36 + bb] + hp[q];
            if (j > 0) x += pre[(q*16 + dd)*36 + bb];
            pv[q] = x;
          }
          float gi = sigf(pv[0]), gf = sigf(pv[1]), go = sigf(pv[2]), gl = sigf(pv[3]);
          float cn = gf * (gl * creg) + gi * tanhfast(pv[4]);
          creg = cn;
          float sn = go * tanhfast(cn);
          AT_ST32(sstream + (size_t)j*16384 + bb*512 + d0 + dd, (gtag<<16) | bf16bits(sn));
        }
        // no fence, no flag, no trailing sync
      }
    }
  } else {
    // ================= logits blocks =================
    u32*   uni  = (u32*)dynlds;
    float* lred = (float*)(dynlds + 32896);
    u64*   kredl= (u64*)(dynlds + 51904);

    const int lb = bid - 32;
    const int v0 = lb * 143;
    int nv = 32000 - v0; if (nv > 143) nv = 143;
    const int grp = tid >> 5, b = tid & 31;
    u16* lu16 = (u16*)uni;
    const u32* slot63 = sstream + (size_t)63*16384;
    const int sidx = (lb*73 + 17) & 16383;

    for (int i = 0; i < 64; ++i){
      const u32 etag = (u32)(i*64 + 64);
      // cheap sentinel poll first (keeps 224 blocks off the slot until ready)
      if (tid == 0){
        long cc = 0;
        while ((AT_LD32(slot63 + sidx) >> 16) != etag){
          __builtin_amdgcn_s_sleep(8);
          if (++cc > (1L<<22)){ bail = 1; break; }
        }
      }
      __syncthreads();
      xspin_llc<0>(slot63, etag, lu16, tid, &bail);
      __syncthreads();
      float acc[9];
      #pragma unroll
      for (int t = 0; t < 9; ++t){
        int vt = grp + 16*t;
        acc[t] = (vt < nv) ? bl[v0 + vt] : -1e30f;
      }
      const u32* srow = uni + b*257;
      for (int pp = 0; pp < 128; ++pp){
        u32 u0 = srow[pp*2], u1 = srow[pp*2 + 1];
        float f0 = lo16(u0), f1 = hi16(u0), f2 = lo16(u1), f3 = hi16(u1);
        #pragma unroll
        for (int t = 0; t < 9; ++t){
          int vt = grp + 16*t;
          if (vt < nv){
            const float4 w4 = *(const float4*)(Wl + (size_t)(v0 + vt)*512 + pp*4);
            acc[t] += f0*w4.x + f1*w4.y + f2*w4.z + f3*w4.w;
          }
        }
      }
      u64 best = 0;
      #pragma unroll
      for (int t = 0; t < 9; ++t){
        int vt = grp + 16*t;
        if (vt < nv){
          lred[vt*33 + b] = acc[t];
          u32 su = __float_as_uint(acc[t]);
          su = (su >> 31) ? ~su : (su | 0x80000000u);
          u64 key = ((u64)su << 32) | (u32)(~(u32)(v0 + vt));
          if (key > best) best = key;
        }
      }
      kredl[grp*32 + b] = best;
      __syncthreads();
      if (tid < 32){
        u64 m = 0;
        #pragma unroll
        for (int q2 = 0; q2 < 16; ++q2){ u64 x = kredl[q2*32 + tid]; if (x > m) m = x; }
        AT_ST64(bests + (size_t)tid*224 + lb, m);
      }
      asm volatile("s_waitcnt vmcnt(0)" ::: "memory");   // bests visible before flag
      if (tid == 0) AT_ST32(donew + (size_t)i*256 + lb, 0x44450000u | (u32)i);
      // output writes AFTER the flag (off the critical path)
      const size_t obase = ((size_t)i*32)*32000 + v0;
      for (int bb2 = 0; bb2 < 32; ++bb2){
        for (int v = tid; v < nv; v += 512)
          out[obase + (size_t)bb2*32000 + v] = lred[v*33 + bb2];
      }
    }
  }
}

__global__ __launch_bounds__(256) void softmax_k(float* __restrict__ out){
  size_t row = blockIdx.x;
  float* p = out + row*32000;
  __shared__ float red[256];
  float s = 0.f;
  for (int v = threadIdx.x; v < 32000; v += 256) s += __expf(p[v]);
  red[threadIdx.x] = s;
  __syncthreads();
  for (int off = 128; off > 0; off >>= 1){
    if (threadIdx.x < off) red[threadIdx.x] += red[threadIdx.x+off];
    __syncthreads();
  }
  float Z = red[0];
  for (int v = threadIdx.x; v < 32000; v += 256) p[v] = __expf(p[v]) / Z;
}

extern "C" void kernel_launch(void* const* d_in, const int* in_sizes, int n_in,
                              void* d_out, int out_size, void* d_ws, size_t ws_size,
                              hipStream_t stream)
{
  const int*   x    = (const int*)d_in[0];
  const float* emb  = (const float*)d_in[2];
  const float* Wihf = (const float*)d_in[3];
  const float* Whhf = (const float*)d_in[4];
  const float* bf   = (const float*)d_in[5];
  const float* Wihb = (const float*)d_in[6];
  const float* Whhb = (const float*)d_in[7];
  const float* bb   = (const float*)d_in[8];
  const float* Wx   = (const float*)d_in[9];
  const float* Ws   = (const float*)d_in[10];
  const float* bc   = (const float*)d_in[11];
  const float* Wl   = (const float*)d_in[12];
  const float* bl   = (const float*)d_in[13];

  char* ws = (char*)d_ws;
  u32* ctrl    = (u32*)ws;                      // 1280 B (encoder gbar)
  u32* donew   = (u32*)(ws + 4096);             // 64 x 256 u32 = 64 KB -> 69632
  u64* bests   = (u64*)(ws + 69632);            // 32 x 224 u64 = 56 KB -> 126976
  u32* sstream = (u32*)(ws + 131072);           // 64 x 16384 u32 = 4 MB -> 4325376
  u32* hbuf    = (u32*)(ws + 4325376);          // 128 KB -> 4456448
  float* emb_x = (float*)(ws + 4456448);        // 4 MB  -> 8650752
  float* h_cat = (float*)(ws + 8650752);        // 8 MB  -> 17039360
  float* GxfP  = (float*)(ws + 17039360);       // 16 MB -> 33816576
  float* GxbP  = (float*)(ws + 33816576);       // 16 MB -> 50593792
  float* hpartT = GxfP;                         // 2560x2048 f32 = 21 MB (Gx dead after encoder)
  u16* Wsbf = (u16*)emb_x;                      // 2.6 MB (emb_x dead after Gx gemms)
  u16* Wxbf = (u16*)h_cat;                      // 2.6 MB (h_cat dead after hpartT gemm)

  hipFuncSetAttribute((const void*)dec_persist,
                      hipFuncAttributeMaxDynamicSharedMemorySize, 141952);

  hipLaunchKernelGGL(init_ctrl, dim3(32), dim3(512), 0, stream, (u32*)ws);
  hipLaunchKernelGGL(embed_k, dim3(4096), dim3(256), 0, stream, x, emb, emb_x);
  hipLaunchKernelGGL(gemm_f32, dim3(8,256), dim3(256), 0, stream,
                     emb_x, 512, Wihf, 512, 0, bf, 0, GxfP, 2048, 512);
  hipLaunchKernelGGL(gemm_f32, dim3(8,256), dim3(256), 0, stream,
                     emb_x, 512, Wihb, 512, 0, bb, 0, GxbP, 2048, 512);
  hipLaunchKernelGGL(enc_persist, dim3(256), dim3(512), 0, stream,
                     Whhf, Whhb, GxfP, GxbP, h_cat, ctrl, hbuf);
  // hpartT[c][t*32+b] = bc[c] + sum_k Wx[c*1536+512+k] * h_cat[(t*32+b)*1024+k]
  hipLaunchKernelGGL(gemm_f32, dim3(8,320), dim3(256), 0, stream,
                     Wx + 512, 1536, h_cat, 1024, 0, bc, 1, hpartT, 2048, 1024);
  hipLaunchKernelGGL(conv_bf16_k, dim3(2560), dim3(256), 0, stream, Ws, 1024, Wsbf);
  hipLaunchKernelGGL(conv_bf16_k, dim3(2560), dim3(256), 0, stream, Wx, 1536, Wxbf);
  hipLaunchKernelGGL(dec_persist, dim3(256), dim3(512), 141952, stream,
                     Wsbf, Wxbf, Wl, bl, emb, hpartT, donew, bests, sstream, (float*)d_out);
  hipLaunchKernelGGL(softmax_k, dim3(2048), dim3(256), 0, stream, (float*)d_out);
}